// Round 8
// baseline (131.608 us; speedup 1.0000x reference)
//
#include <hip/hip_runtime.h>

// Problem constants (from setup_inputs): N=4096, C=64, A=256
#define N_ROWS 4096
#define C_CLS  64
#define A_DIM  256
#define KCHUNK 8            // now an A-column chunking (8 x 32 a-cols)
#define LOSS_BLOCKS 256     // kernel B blocks (4 waves each, 4 rows/wave)

// ---------------------------------------------------------------------------
// Session ledger (rounds 0-7):
//  - fixed harness overhead ~62 us (256 MiB poison fill ~44 us + resets).
//  - grid barriers 30-75 us (r1-2): dead end. Ticket-merge neutral (r3).
//  - occupancy/tile reshapes neutral (r5-6).
//  - SLOPE PROBE (r7): 3x A launches -> +21 us => t_A_warm ~10.5 us, ~3x its
//    3.4 us VALU floor, LLC-warm. Diagnosis: inner loop issues 4 ds_read_b128
//    per 64 FMA = 262K wave-reads @ ~12cyc = ~5.1 us/CU of LDS-pipe
//    serialization, 8-way broadcast-redundant. LDS inst count per FMA never
//    changed across r5/r6 reshapes -> why they were neutral.
//  THIS ROUND: LDS-free inner loop. lane=c streams W[c][:] in registers;
//  CV[y][b][a-tile] + W[y][b] are wave-uniform -> readfirstlane-forced
//  s_load -> SGPR operand of v_fma. 1 sub + 8 FMA per b, zero LDS.
// ---------------------------------------------------------------------------

// ---------------------------------------------------------------------------
// Kernel A: Spart[ab][y][c] = sum over a-chunk ab of T[c,a]*D[c,a], where
// T[c,a] = sum_{b=0..255} D[c,b]*CV[y][b][a]  (full b-sum, ref-ordered)
// block = (y, 32-a-chunk): grid 512, 256 thr (4 waves x 8 a-cols each).
// ---------------------------------------------------------------------------
__global__ __launch_bounds__(256) void qform_kernel(
    const float* __restrict__ W,      // [C][A]
    const float* __restrict__ CV,     // [C][A][A]
    float* __restrict__ Spart)        // [KCHUNK][C][C]
{
    __shared__ float Psum[4][C_CLS];  // 1 KB: per-wave partial S

    const int t    = threadIdx.x;
    const int lane = t & 63;                                   // lane = class c
    const int wv   = __builtin_amdgcn_readfirstlane(t >> 6);   // wave 0..3 (scalar)
    const int y    = blockIdx.x >> 3;                          // scalar
    const int ab   = blockIdx.x & 7;                           // a-32 chunk (scalar)
    const int a0   = ab * 32 + wv * 8;                         // scalar

    // scalar bases -> s_load; per-lane base -> vector loads
    const float* __restrict__ cvp = CV + (size_t)y * A_DIM * A_DIM + a0;
    const float* __restrict__ wyp = W + y * A_DIM;
    const float* __restrict__ wcp = W + lane * A_DIM;

    float acc[8];
    #pragma unroll
    for (int j = 0; j < 8; ++j) acc[j] = 0.0f;

    // ping-pong 32-float chunks of this lane's W row (L1-hot: all waves share W)
    float cur[32], nxt[32];
    #pragma unroll
    for (int i = 0; i < 8; ++i) {
        const float4 v = ((const float4*)wcp)[i];
        cur[4*i+0] = v.x; cur[4*i+1] = v.y; cur[4*i+2] = v.z; cur[4*i+3] = v.w;
    }

    #pragma unroll 1
    for (int pc = 0; pc < 4; ++pc) {          // 2 x 32-b chunks per iter
        const int b0 = pc * 64;

        // prefetch chunk 2pc+1 into nxt (always valid: <= 7)
        #pragma unroll
        for (int i = 0; i < 8; ++i) {
            const float4 v = ((const float4*)wcp)[(2*pc+1)*8 + i];
            nxt[4*i+0] = v.x; nxt[4*i+1] = v.y; nxt[4*i+2] = v.z; nxt[4*i+3] = v.w;
        }
        // compute chunk 2pc (cur): b = b0 .. b0+31
        #pragma unroll
        for (int bi = 0; bi < 32; ++bi) {
            const int b = b0 + bi;
            const float d = cur[bi] - wyp[b];                 // wyp[b]: s_load
            #pragma unroll
            for (int j = 0; j < 8; ++j)                       // cvp[..]: s_load
                acc[j] = fmaf(d, cvp[(size_t)b * A_DIM + j], acc[j]);
        }

        // prefetch chunk min(2pc+2, 7) into cur (clamped: branch-free, no OOB)
        const int nc = (2*pc + 2 < 8) ? (2*pc + 2) : 7;
        #pragma unroll
        for (int i = 0; i < 8; ++i) {
            const float4 v = ((const float4*)wcp)[nc*8 + i];
            cur[4*i+0] = v.x; cur[4*i+1] = v.y; cur[4*i+2] = v.z; cur[4*i+3] = v.w;
        }
        // compute chunk 2pc+1 (nxt): b = b0+32 .. b0+63
        #pragma unroll
        for (int bi = 0; bi < 32; ++bi) {
            const int b = b0 + 32 + bi;
            const float d = nxt[bi] - wyp[b];
            #pragma unroll
            for (int j = 0; j < 8; ++j)
                acc[j] = fmaf(d, cvp[(size_t)b * A_DIM + j], acc[j]);
        }
    }

    // epilogue: s = sum_j T[c][a0+j] * (W[c][a0+j] - W[y][a0+j])
    float s = 0.0f;
    {
        const float4 wa_lo = *(const float4*)(wcp + a0);
        const float4 wa_hi = *(const float4*)(wcp + a0 + 4);
        const float wav[8] = {wa_lo.x, wa_lo.y, wa_lo.z, wa_lo.w,
                              wa_hi.x, wa_hi.y, wa_hi.z, wa_hi.w};
        #pragma unroll
        for (int j = 0; j < 8; ++j)
            s = fmaf(acc[j], wav[j] - wyp[a0 + j], s);
    }
    Psum[wv][lane] = s;          // 2 lanes/bank: conflict-free
    __syncthreads();

    if (t < C_CLS) {
        const float r = Psum[0][t] + Psum[1][t] + Psum[2][t] + Psum[3][t];
        Spart[(size_t)ab * C_CLS * C_CLS + y * C_CLS + t] = r;
    }
}

// ---------------------------------------------------------------------------
// Kernel B: per-row softmax CE on aug = pred + 0.5*Lambda*sum_k Spart[k][y].
// One wave per row, 4 waves/block, 4 rows per wave; per-block partial to ws.
// Round-0 verbatim (sum over KCHUNK now spans a-chunks; same value).
// ---------------------------------------------------------------------------
__global__ __launch_bounds__(256) void loss_kernel(
    const float* __restrict__ pred,    // [N][C]
    const int*   __restrict__ labels,  // [N]
    const float* __restrict__ lambda_p,
    const float* __restrict__ Spart,   // [KCHUNK][C][C]
    float* __restrict__ partials)      // [LOSS_BLOCKS]
{
    __shared__ float wsum[4];
    const int t    = threadIdx.x;
    const int lane = t & 63;
    const int wgid = blockIdx.x * 4 + (t >> 6);   // global wave id, 0..1023
    const float lam = 0.5f * lambda_p[0];

    float acc_nll = 0.0f;
    #pragma unroll
    for (int r = 0; r < 4; ++r) {
        const int n = r * 1024 + wgid;
        const int y = labels[n];
        float sp = 0.0f;
        #pragma unroll
        for (int k = 0; k < KCHUNK; ++k)
            sp += Spart[(size_t)k * C_CLS * C_CLS + y * C_CLS + lane];
        const float logit = pred[n * C_CLS + lane] + lam * sp;

        float m = logit;
        #pragma unroll
        for (int off = 32; off > 0; off >>= 1)
            m = fmaxf(m, __shfl_xor(m, off, 64));
        float e = __expf(logit - m);
        float ssum = e;
        #pragma unroll
        for (int off = 32; off > 0; off >>= 1)
            ssum += __shfl_xor(ssum, off, 64);
        const float ly = __shfl(logit, y, 64);
        acc_nll += logf(ssum) + m - ly;
    }

    if (lane == 0) wsum[t >> 6] = acc_nll;
    __syncthreads();
    if (t == 0)
        partials[blockIdx.x] = wsum[0] + wsum[1] + wsum[2] + wsum[3];
}

// ---------------------------------------------------------------------------
// Kernel C: reduce 256 block partials -> mean loss. One block. Round-0 verbatim.
// ---------------------------------------------------------------------------
__global__ __launch_bounds__(256) void finalize_kernel(
    const float* __restrict__ partials, float* __restrict__ out)
{
    __shared__ float wsum[4];
    const int t = threadIdx.x;
    float v = partials[t];
    #pragma unroll
    for (int off = 32; off > 0; off >>= 1)
        v += __shfl_xor(v, off, 64);
    if ((t & 63) == 0) wsum[t >> 6] = v;
    __syncthreads();
    if (t == 0)
        out[0] = (wsum[0] + wsum[1] + wsum[2] + wsum[3]) * (1.0f / (float)N_ROWS);
}

// ---------------------------------------------------------------------------
extern "C" void kernel_launch(void* const* d_in, const int* in_sizes, int n_in,
                              void* d_out, int out_size, void* d_ws, size_t ws_size,
                              hipStream_t stream) {
    (void)in_sizes; (void)n_in; (void)out_size; (void)ws_size;
    const float* W      = (const float*)d_in[0];   // fc_weight [64][256]
    // d_in[1] = features (unused by the reference computation)
    const float* pred   = (const float*)d_in[2];   // [4096][64]
    const int*   labels = (const int*)d_in[3];     // [4096]
    const float* lam    = (const float*)d_in[4];   // scalar
    const float* CV     = (const float*)d_in[5];   // [64][256][256]
    float* out = (float*)d_out;

    float* Spart    = (float*)d_ws;                             // 8*64*64 floats = 128 KB
    float* partials = (float*)d_ws + KCHUNK * C_CLS * C_CLS;    // 256 floats

    qform_kernel<<<dim3(C_CLS * KCHUNK), dim3(256), 0, stream>>>(W, CV, Spart);
    loss_kernel<<<dim3(LOSS_BLOCKS), dim3(256), 0, stream>>>(pred, labels, lam, Spart, partials);
    finalize_kernel<<<dim3(1), dim3(256), 0, stream>>>(partials, out);
}

// Round 10
// 94.112 us; speedup vs baseline: 1.3984x; 1.3984x over previous
//
#include <hip/hip_runtime.h>

// Problem constants (from setup_inputs): N=4096, C=64, A=256
#define N_ROWS 4096
#define C_CLS  64
#define A_DIM  256
#define BK     32           // K-chunk (over b) per block in kernel A
#define KCHUNK (A_DIM / BK) // 8
#define LOSS_BLOCKS 512     // kernel B blocks (4 waves each, 2 rows/wave)

// ---------------------------------------------------------------------------
// Session ledger (rounds 0-9):
//  - serial cost model: ~18 us resets + ~44 us ws poison fill + our kernels.
//  - r0 (best, 88.8): kernels ~26.8 us. r7 slope probe: A+gap = 10.5 us
//    -> tail (B+C+gaps) ~16.3 us vs ~4 us floor => tail is the big slack.
//  - A-side attacks all failed: grid barriers 30-75us (r1/r2), BK16 (r3/r5),
//    4x8/512thr tile (r6), SGPR-scalarized CV (r8: 71-78us, s_load latency
//    serializes). A stays r0-exact (LDS-bound ~8.5us, accepted).
//  - r9: infra failure (container), no data — identical resubmission.
//  THIS ROUND (tail): kill kernel C via ticket-merge into B (removes one
//  graph-node boundary + a 1-block dispatch ramp); B at 512 blocks x 2
//  rows/wave (8 waves/CU) to halve serial latency chains.
// ---------------------------------------------------------------------------
__device__ float    g_part[LOSS_BLOCKS]; // per-block loss partials
__device__ unsigned g_tick = 0;          // monotonic ticket: +512/launch, no reset
                                         // needed (graph/rocprof-replay safe)

// ---------------------------------------------------------------------------
// Kernel A: Spart[kc][y][c] = partial over b-chunk of (w_c-w_y)^T CV[y] (w_c-w_y)
// Round-0 verbatim (measured best).
// ---------------------------------------------------------------------------
__global__ __launch_bounds__(256) void qform_kernel(
    const float* __restrict__ W,      // [C][A]
    const float* __restrict__ CV,     // [C][A][A]
    float* __restrict__ Spart)        // [KCHUNK][C][C]
{
    __shared__ float Vt[BK][A_DIM];   // 32 KB
    __shared__ float Dt[BK][C_CLS];   //  8 KB
    __shared__ float Psum[32][C_CLS]; //  8 KB

    const int t  = threadIdx.x;
    const int y  = blockIdx.x >> 3;
    const int kc = blockIdx.x & 7;
    const int kb = kc * BK;

    {
        const float4* src = (const float4*)(CV + ((size_t)y * A_DIM * A_DIM
                                                  + (size_t)kb * A_DIM));
        float4* vdst = (float4*)&Vt[0][0];
        #pragma unroll
        for (int i = 0; i < (BK * A_DIM / 4) / 256; ++i)
            vdst[t + i * 256] = src[t + i * 256];
    }

    {
        const int kq    = (t & 7) * 4;
        const int chalf = t >> 3;
        const float4 wy = *(const float4*)(W + y * A_DIM + kb + kq);
        #pragma unroll
        for (int cc = 0; cc < 2; ++cc) {
            const int c = chalf + cc * 32;
            const float4 wc = *(const float4*)(W + c * A_DIM + kb + kq);
            Dt[kq + 0][c] = wc.x - wy.x;
            Dt[kq + 1][c] = wc.y - wy.y;
            Dt[kq + 2][c] = wc.z - wy.z;
            Dt[kq + 3][c] = wc.w - wy.w;
        }
    }
    __syncthreads();

    const int c0 = (t & 7) * 8;
    const int a0 = (t >> 3) * 8;
    float acc[8][8];
    #pragma unroll
    for (int i = 0; i < 8; ++i)
        #pragma unroll
        for (int j = 0; j < 8; ++j) acc[i][j] = 0.0f;

    #pragma unroll 2
    for (int k = 0; k < BK; ++k) {
        const float4 a_lo = *(const float4*)&Vt[k][a0];
        const float4 a_hi = *(const float4*)&Vt[k][a0 + 4];
        const float4 d_lo = *(const float4*)&Dt[k][c0];
        const float4 d_hi = *(const float4*)&Dt[k][c0 + 4];
        const float af[8] = {a_lo.x, a_lo.y, a_lo.z, a_lo.w,
                             a_hi.x, a_hi.y, a_hi.z, a_hi.w};
        const float df[8] = {d_lo.x, d_lo.y, d_lo.z, d_lo.w,
                             d_hi.x, d_hi.y, d_hi.z, d_hi.w};
        #pragma unroll
        for (int i = 0; i < 8; ++i)
            #pragma unroll
            for (int j = 0; j < 8; ++j)
                acc[i][j] += df[i] * af[j];
    }

    float s[8];
    {
        const float4 wy_lo = *(const float4*)(W + y * A_DIM + a0);
        const float4 wy_hi = *(const float4*)(W + y * A_DIM + a0 + 4);
        const float wyv[8] = {wy_lo.x, wy_lo.y, wy_lo.z, wy_lo.w,
                              wy_hi.x, wy_hi.y, wy_hi.z, wy_hi.w};
        #pragma unroll
        for (int i = 0; i < 8; ++i) {
            const int c = c0 + i;
            const float4 wc_lo = *(const float4*)(W + c * A_DIM + a0);
            const float4 wc_hi = *(const float4*)(W + c * A_DIM + a0 + 4);
            const float wcv[8] = {wc_lo.x, wc_lo.y, wc_lo.z, wc_lo.w,
                                  wc_hi.x, wc_hi.y, wc_hi.z, wc_hi.w};
            float ss = 0.0f;
            #pragma unroll
            for (int j = 0; j < 8; ++j)
                ss += acc[i][j] * (wcv[j] - wyv[j]);
            s[i] = ss;
        }
    }
    const int ag = t >> 3;
    *(float4*)&Psum[ag][c0]     = make_float4(s[0], s[1], s[2], s[3]);
    *(float4*)&Psum[ag][c0 + 4] = make_float4(s[4], s[5], s[6], s[7]);
    __syncthreads();

    if (t < C_CLS) {
        float r = 0.0f;
        #pragma unroll
        for (int g = 0; g < 32; ++g) r += Psum[g][t];
        Spart[(size_t)kc * C_CLS * C_CLS + y * C_CLS + t] = r;
    }
}

// ---------------------------------------------------------------------------
// Kernel B: per-row softmax CE + ticket-merged finalize.
// 512 blocks x 4 waves x 2 rows/wave (8 waves/CU): halves the per-wave serial
// label->Spart->softmax chain vs round-0's 4 rows/wave. Last block (relaxed
// agent-scope ticket, mechanics proven r2/r3) reduces 512 partials in a fixed
// deterministic order and writes the mean loss.
// ---------------------------------------------------------------------------
__global__ __launch_bounds__(256) void loss_kernel(
    const float* __restrict__ pred,    // [N][C]
    const int*   __restrict__ labels,  // [N]
    const float* __restrict__ lambda_p,
    const float* __restrict__ Spart,   // [KCHUNK][C][C]
    float* __restrict__ out)
{
    __shared__ float wsum[4];
    __shared__ int   s_last;

    const int t    = threadIdx.x;
    const int lane = t & 63;
    const int wv   = t >> 6;
    const int gw   = (int)blockIdx.x * 4 + wv;    // 0..2047
    const float lam = 0.5f * lambda_p[0];

    // ---- hoist both rows' independent loads up front ----
    const int n0 = gw, n1 = gw + 2048;
    const int y0 = labels[n0];
    const int y1 = labels[n1];
    const float p0 = pred[n0 * C_CLS + lane];
    const float p1 = pred[n1 * C_CLS + lane];
    float sp0 = 0.0f, sp1 = 0.0f;
    #pragma unroll
    for (int k = 0; k < KCHUNK; ++k) {
        sp0 += Spart[(size_t)k * C_CLS * C_CLS + y0 * C_CLS + lane];
        sp1 += Spart[(size_t)k * C_CLS * C_CLS + y1 * C_CLS + lane];
    }

    float acc_nll = 0.0f;
    {
        const float logit = p0 + lam * sp0;
        float m = logit;
        #pragma unroll
        for (int off = 32; off > 0; off >>= 1)
            m = fmaxf(m, __shfl_xor(m, off, 64));
        float e = __expf(logit - m);
        float ssum = e;
        #pragma unroll
        for (int off = 32; off > 0; off >>= 1)
            ssum += __shfl_xor(ssum, off, 64);
        acc_nll += logf(ssum) + m - __shfl(logit, y0, 64);
    }
    {
        const float logit = p1 + lam * sp1;
        float m = logit;
        #pragma unroll
        for (int off = 32; off > 0; off >>= 1)
            m = fmaxf(m, __shfl_xor(m, off, 64));
        float e = __expf(logit - m);
        float ssum = e;
        #pragma unroll
        for (int off = 32; off > 0; off >>= 1)
            ssum += __shfl_xor(ssum, off, 64);
        acc_nll += logf(ssum) + m - __shfl(logit, y1, 64);
    }

    if (lane == 0) wsum[wv] = acc_nll;
    __syncthreads();
    if (t == 0) {
        // sc1 store lands at the LLC (agent coherence point); vmcnt drain
        // orders it before the ticket RMW. No cache sweeps (relaxed only).
        __hip_atomic_store(&g_part[blockIdx.x],
                           wsum[0] + wsum[1] + wsum[2] + wsum[3],
                           __ATOMIC_RELAXED, __HIP_MEMORY_SCOPE_AGENT);
        asm volatile("s_waitcnt vmcnt(0)" ::: "memory");
        unsigned v = __hip_atomic_fetch_add(&g_tick, 1u, __ATOMIC_RELAXED,
                                            __HIP_MEMORY_SCOPE_AGENT) + 1u;
        s_last = ((v & (LOSS_BLOCKS - 1u)) == 0u) ? 1 : 0;
    }
    __syncthreads();

    // ---- last block: deterministic reduce of 512 partials -> mean loss ----
    if (s_last) {
        float v = __hip_atomic_load(&g_part[t], __ATOMIC_RELAXED,
                                    __HIP_MEMORY_SCOPE_AGENT)
                + __hip_atomic_load(&g_part[t + 256], __ATOMIC_RELAXED,
                                    __HIP_MEMORY_SCOPE_AGENT);
        #pragma unroll
        for (int off = 32; off > 0; off >>= 1)
            v += __shfl_xor(v, off, 64);
        if (lane == 0) wsum[wv] = v;
        __syncthreads();
        if (t == 0)
            out[0] = (wsum[0] + wsum[1] + wsum[2] + wsum[3])
                     * (1.0f / (float)N_ROWS);
    }
}

// ---------------------------------------------------------------------------
extern "C" void kernel_launch(void* const* d_in, const int* in_sizes, int n_in,
                              void* d_out, int out_size, void* d_ws, size_t ws_size,
                              hipStream_t stream) {
    (void)in_sizes; (void)n_in; (void)out_size; (void)ws_size;
    const float* W      = (const float*)d_in[0];   // fc_weight [64][256]
    // d_in[1] = features (unused by the reference computation)
    const float* pred   = (const float*)d_in[2];   // [4096][64]
    const int*   labels = (const int*)d_in[3];     // [4096]
    const float* lam    = (const float*)d_in[4];   // scalar
    const float* CV     = (const float*)d_in[5];   // [64][256][256]
    float* out = (float*)d_out;

    float* Spart = (float*)d_ws;   // 8*64*64 floats = 128 KB (written before read)

    qform_kernel<<<dim3(C_CLS * KCHUNK), dim3(256), 0, stream>>>(W, CV, Spart);
    loss_kernel<<<dim3(LOSS_BLOCKS), dim3(256), 0, stream>>>(pred, labels, lam, Spart, out);
}